// Round 6
// baseline (469.891 us; speedup 1.0000x reference)
//
#include <hip/hip_runtime.h>
#include <hip/hip_bf16.h>

#define NE 8
#define HD 1024
#define ID 2816
#define TT 4096
#define BM 128
#define BK 32
#define BN1 128
#define BN2 64
#define MAXMT (TT / BM + NE) /* 40 worst-case M-tiles */

typedef __attribute__((ext_vector_type(4))) float f32x4;
typedef __attribute__((ext_vector_type(8))) short s16x8;

// fp32x2 -> packed bf16x2 (RNE, v_cvt_pk_bf16_f32)
__device__ __forceinline__ unsigned int f2bfpk(float lo, float hi) {
  float2 t; t.x = lo; t.y = hi;
  union { __hip_bfloat162 h2; unsigned int u; } cv;
  cv.h2 = __float22bfloat162_rn(t);
  return cv.u;
}

// barrier that does NOT drain vmcnt: prefetch loads stay in flight
__device__ __forceinline__ void lds_barrier() {
  asm volatile("s_waitcnt lgkmcnt(0)" ::: "memory");
  __builtin_amdgcn_s_barrier();
}

__device__ __forceinline__ bool map_tile(const void* bsp, int mt, int& e,
                                         int& mstart, int& rowend) {
  const int* w = (const int*)bsp;
  bool is64 = (w[1] == 0) && (w[3] == 0) && (w[5] == 0) && (w[7] == 0) &&
              ((w[0] | w[2] | w[4] | w[6]) != 0);
  long long start = 0;
  int rem = mt;
  for (int i = 0; i < NE; ++i) {
    long long b = is64 ? ((const long long*)bsp)[i] : (long long)w[i];
    if (b < 0) b = 0;
    int tiles = (int)((b + BM - 1) / BM);
    if (rem < tiles) {
      long long m0 = start + (long long)rem * BM;
      long long me = start + b;
      if (m0 >= TT) return false;
      if (me > TT) me = TT;
      e = i; mstart = (int)m0; rowend = (int)me;
      return true;
    }
    rem -= tiles;
    start += b;
  }
  return false;
}

// ---------------- Kernel 0: x (fp32) -> xbf (bf16) ----------------
__global__ __launch_bounds__(256) void cvt_x(const float* __restrict__ x,
                                             __hip_bfloat16* __restrict__ xb) {
  size_t i = ((size_t)blockIdx.x * 256 + threadIdx.x) * 8;
  f32x4 v0 = *(const f32x4*)(x + i);
  f32x4 v1 = *(const f32x4*)(x + i + 4);
  s16x8 o;
  unsigned int p0 = f2bfpk(v0[0], v0[1]), p1 = f2bfpk(v0[2], v0[3]);
  unsigned int p2 = f2bfpk(v1[0], v1[1]), p3 = f2bfpk(v1[2], v1[3]);
  o[0] = (short)(p0 & 0xffff); o[1] = (short)(p0 >> 16);
  o[2] = (short)(p1 & 0xffff); o[3] = (short)(p1 >> 16);
  o[4] = (short)(p2 & 0xffff); o[5] = (short)(p2 >> 16);
  o[6] = (short)(p3 & 0xffff); o[7] = (short)(p3 >> 16);
  *(s16x8*)((unsigned short*)xb + i) = o;
}

// ---------------- Kernel 1: up = silu(x@w1[e]) * (x@w3[e]) ----------------
// 512 threads, 128x128 tile, 8 waves (2m x 4n), BK=32, dual accumulators.
// B LDS: [n][80B], k 16B-contiguous -> b128 frag reads, b64 writes.
// 2-deep prefetch, vmcnt-preserving lds_barrier, 1 barrier per k-step.
__global__ __launch_bounds__(512, 4) void moe_gemm1(
    const __hip_bfloat16* __restrict__ xbf, const float* __restrict__ w1,
    const float* __restrict__ w3, const void* __restrict__ bsp,
    __hip_bfloat16* __restrict__ up) {
  __shared__ __align__(16) char As[2][BM * 80];    // 20480
  __shared__ __align__(16) char B1s[2][BN1 * 80];  // 20480
  __shared__ __align__(16) char B3s[2][BN1 * 80];  // 20480

  const int NWG = (ID / BN1) * MAXMT;  // 22*40 = 880, %8==0
  int bid = blockIdx.x;
  int logical = (bid & 7) * (NWG >> 3) + (bid >> 3);
  int mt = logical % MAXMT;
  int nt = logical / MAXMT;
  int e, mstart, rowend;
  if (!map_tile(bsp, mt, e, mstart, rowend)) return;
  const int n0 = nt * BN1;
  const int tid = threadIdx.x;

  const int lane = tid & 63;
  const int wv = tid >> 6;          // 0..7
  const int wr = wv >> 2, wc = wv & 3;  // 2m x 4n, per-wave 64m x 32n
  const int q = lane >> 4, r16 = lane & 15;

  // staging geometry (512 threads)
  const int a_k8 = (tid & 3) * 8;   // bf16 k-offset (16B)
  const int a_r0 = tid >> 2;        // 0..127
  const int b_n = tid & 127;        // B column
  const int b_kq = tid >> 7;        // 0..3 (k-quad)

  const bool ok0 = (mstart + a_r0) < rowend;

  const __hip_bfloat16* xc = xbf + (size_t)(mstart + a_r0) * HD + a_k8;
  const float* w1c = w1 + (size_t)e * HD * ID + (size_t)(4 * b_kq) * ID + n0 + b_n;
  const float* w3c = w3 + (size_t)e * HD * ID + (size_t)(4 * b_kq) * ID + n0 + b_n;

  f32x4 acc1[4][2], acc3[4][2];
#pragma unroll
  for (int i = 0; i < 4; ++i)
#pragma unroll
    for (int j = 0; j < 2; ++j) { acc1[i][j] = (f32x4)0.f; acc3[i][j] = (f32x4)0.f; }

  // two register prefetch buffers (statically indexed)
  s16x8 A0, A1;
  float W1a[2][4], W3a[2][4], W1b[2][4], W3b[2][4];

  auto load_t = [&](s16x8& A, float (*W1_)[4], float (*W3_)[4]) {
    A = ok0 ? *(const s16x8*)xc : (s16x8)0;
    xc += BK;
#pragma unroll
    for (int g = 0; g < 2; ++g)
#pragma unroll
      for (int kk = 0; kk < 4; ++kk) {
        W1_[g][kk] = w1c[(size_t)(g * 16 + kk) * ID];
        W3_[g][kk] = w3c[(size_t)(g * 16 + kk) * ID];
      }
    w1c += (size_t)BK * ID; w3c += (size_t)BK * ID;
  };
  auto store_t = [&](char* As_, char* B1_, char* B3_, const s16x8& A,
                     const float (*W1_)[4], const float (*W3_)[4]) {
    *(s16x8*)(As_ + a_r0 * 80 + a_k8 * 2) = A;
#pragma unroll
    for (int g = 0; g < 2; ++g) {
      unsigned long long p1 =
          (unsigned long long)f2bfpk(W1_[g][0], W1_[g][1]) |
          ((unsigned long long)f2bfpk(W1_[g][2], W1_[g][3]) << 32);
      *(unsigned long long*)(B1_ + b_n * 80 + b_kq * 8 + g * 32) = p1;
      unsigned long long p3 =
          (unsigned long long)f2bfpk(W3_[g][0], W3_[g][1]) |
          ((unsigned long long)f2bfpk(W3_[g][2], W3_[g][3]) << 32);
      *(unsigned long long*)(B3_ + b_n * 80 + b_kq * 8 + g * 32) = p3;
    }
  };
  auto compute_t = [&](const char* As_, const char* B1_, const char* B3_) {
    s16x8 a[4], b1[2], b3[2];
#pragma unroll
    for (int i = 0; i < 4; ++i)
      a[i] = *(const s16x8*)(As_ + (wr * 64 + i * 16 + r16) * 80 + q * 16);
#pragma unroll
    for (int j = 0; j < 2; ++j) {
      b1[j] = *(const s16x8*)(B1_ + (wc * 32 + j * 16 + r16) * 80 + q * 16);
      b3[j] = *(const s16x8*)(B3_ + (wc * 32 + j * 16 + r16) * 80 + q * 16);
    }
#pragma unroll
    for (int i = 0; i < 4; ++i)
#pragma unroll
      for (int j = 0; j < 2; ++j) {
        acc1[i][j] = __builtin_amdgcn_mfma_f32_16x16x32_bf16(a[i], b1[j], acc1[i][j], 0, 0, 0);
        acc3[i][j] = __builtin_amdgcn_mfma_f32_16x16x32_bf16(a[i], b3[j], acc3[i][j], 0, 0, 0);
      }
  };

  const int NK = HD / BK;  // 32 (even)
  load_t(A0, W1a, W3a);
  load_t(A1, W1b, W3b);
  store_t(As[0], B1s[0], B3s[0], A0, W1a, W3a);
  lds_barrier();
  for (int kt = 0; kt < NK; kt += 2) {
    if (kt + 2 < NK) load_t(A0, W1a, W3a);
    compute_t(As[0], B1s[0], B3s[0]);
    store_t(As[1], B1s[1], B3s[1], A1, W1b, W3b);
    lds_barrier();
    if (kt + 3 < NK) load_t(A1, W1b, W3b);
    compute_t(As[1], B1s[1], B3s[1]);
    if (kt + 2 < NK) {
      store_t(As[0], B1s[0], B3s[0], A0, W1a, W3a);
      lds_barrier();
    }
  }

  // epilogue: silu(acc1)*acc3 -> bf16
#pragma unroll
  for (int i = 0; i < 4; ++i)
#pragma unroll
    for (int r = 0; r < 4; ++r) {
      int gm = mstart + wr * 64 + i * 16 + q * 4 + r;
      if (gm < rowend) {
#pragma unroll
        for (int j = 0; j < 2; ++j) {
          float v1 = acc1[i][j][r], v3 = acc3[i][j][r];
          float s = v1 / (1.f + __expf(-v1));
          up[(size_t)gm * ID + n0 + wc * 32 + j * 16 + r16] = __float2bfloat16(s * v3);
        }
      }
    }
}

// ---------------- Kernel 2: out = up @ w2[e] ----------------
// 256 threads, 128x64 tile, 4 waves (2m x 2n). Same B layout fixes.
__global__ __launch_bounds__(256, 4) void moe_gemm2(
    const __hip_bfloat16* __restrict__ up, const float* __restrict__ w2,
    const void* __restrict__ bsp, float* __restrict__ out) {
  __shared__ __align__(16) char As[2][BM * 80];   // 20480
  __shared__ __align__(16) char Bs[2][BN2 * 80];  // 10240

  const int NWG = (HD / BN2) * MAXMT;  // 640, %8==0
  int bid = blockIdx.x;
  int logical = (bid & 7) * (NWG >> 3) + (bid >> 3);
  int mt = logical % MAXMT;
  int nt = logical / MAXMT;
  int e, mstart, rowend;
  if (!map_tile(bsp, mt, e, mstart, rowend)) return;
  const int n0 = nt * BN2;
  const int tid = threadIdx.x;

  const int lane = tid & 63;
  const int wv = tid >> 6;
  const int wr = wv >> 1, wc = wv & 1;
  const int q = lane >> 4, r16 = lane & 15;

  const int a_k8 = (tid & 3) * 8;
  const int a_r0 = tid >> 2;   // 0..63, rows {a_r0, a_r0+64}
  const int b_n = tid & 63;
  const int b_kq = tid >> 6;   // 0..3

  const bool ok0 = (mstart + a_r0) < rowend;
  const bool ok1 = (mstart + a_r0 + 64) < rowend;

  const __hip_bfloat16* uc = up + (size_t)(mstart + a_r0) * ID + a_k8;
  const float* w2c = w2 + (size_t)e * ID * HD + (size_t)(4 * b_kq) * HD + n0 + b_n;

  f32x4 acc[4][2];
#pragma unroll
  for (int i = 0; i < 4; ++i)
#pragma unroll
    for (int j = 0; j < 2; ++j) acc[i][j] = (f32x4)0.f;

  s16x8 A0[2], A1[2];
  float Wa[2][4], Wb[2][4];

  auto load_t = [&](s16x8* A, float (*W_)[4]) {
    A[0] = ok0 ? *(const s16x8*)uc : (s16x8)0;
    A[1] = ok1 ? *(const s16x8*)(uc + (size_t)64 * ID) : (s16x8)0;
    uc += BK;
#pragma unroll
    for (int g = 0; g < 2; ++g)
#pragma unroll
      for (int kk = 0; kk < 4; ++kk)
        W_[g][kk] = w2c[(size_t)(g * 16 + kk) * HD];
    w2c += (size_t)BK * HD;
  };
  auto store_t = [&](char* As_, char* B_, const s16x8* A, const float (*W_)[4]) {
    *(s16x8*)(As_ + a_r0 * 80 + a_k8 * 2) = A[0];
    *(s16x8*)(As_ + (a_r0 + 64) * 80 + a_k8 * 2) = A[1];
#pragma unroll
    for (int g = 0; g < 2; ++g) {
      unsigned long long p =
          (unsigned long long)f2bfpk(W_[g][0], W_[g][1]) |
          ((unsigned long long)f2bfpk(W_[g][2], W_[g][3]) << 32);
      *(unsigned long long*)(B_ + b_n * 80 + b_kq * 8 + g * 32) = p;
    }
  };
  auto compute_t = [&](const char* As_, const char* B_) {
    s16x8 a[4], b[2];
#pragma unroll
    for (int i = 0; i < 4; ++i)
      a[i] = *(const s16x8*)(As_ + (wr * 64 + i * 16 + r16) * 80 + q * 16);
#pragma unroll
    for (int j = 0; j < 2; ++j)
      b[j] = *(const s16x8*)(B_ + (wc * 32 + j * 16 + r16) * 80 + q * 16);
#pragma unroll
    for (int i = 0; i < 4; ++i)
#pragma unroll
      for (int j = 0; j < 2; ++j)
        acc[i][j] = __builtin_amdgcn_mfma_f32_16x16x32_bf16(a[i], b[j], acc[i][j], 0, 0, 0);
  };

  const int NK = ID / BK;  // 88 (even)
  load_t(A0, Wa);
  load_t(A1, Wb);
  store_t(As[0], Bs[0], A0, Wa);
  lds_barrier();
  for (int kt = 0; kt < NK; kt += 2) {
    if (kt + 2 < NK) load_t(A0, Wa);
    compute_t(As[0], Bs[0]);
    store_t(As[1], Bs[1], A1, Wb);
    lds_barrier();
    if (kt + 3 < NK) load_t(A1, Wb);
    compute_t(As[1], Bs[1]);
    if (kt + 2 < NK) {
      store_t(As[0], Bs[0], A0, Wa);
      lds_barrier();
    }
  }

#pragma unroll
  for (int i = 0; i < 4; ++i)
#pragma unroll
    for (int r = 0; r < 4; ++r) {
      int gm = mstart + wr * 64 + i * 16 + q * 4 + r;
      if (gm < rowend) {
#pragma unroll
        for (int j = 0; j < 2; ++j)
          out[(size_t)gm * HD + n0 + wc * 32 + j * 16 + r16] = acc[i][j][r];
      }
    }
}

extern "C" void kernel_launch(void* const* d_in, const int* in_sizes, int n_in,
                              void* d_out, int out_size, void* d_ws, size_t ws_size,
                              hipStream_t stream) {
  const float* x = (const float*)d_in[0];
  const float* w1 = (const float*)d_in[1];
  const float* w2 = (const float*)d_in[2];
  const float* w3 = (const float*)d_in[3];
  const void* bs = d_in[4];
  float* out = (float*)d_out;
  // ws layout: xbf [TT*HD bf16 = 8.39 MB] | up [TT*ID bf16 = 23.1 MB]
  __hip_bfloat16* xbf = (__hip_bfloat16*)d_ws;
  __hip_bfloat16* up = (__hip_bfloat16*)((char*)d_ws + (size_t)TT * HD * 2);

  hipMemsetAsync(d_out, 0, (size_t)out_size * sizeof(float), stream);

  cvt_x<<<dim3(TT * HD / (8 * 256)), dim3(256), 0, stream>>>(x, xbf);
  moe_gemm1<<<dim3((ID / BN1) * MAXMT), dim3(512), 0, stream>>>(xbf, w1, w3, bs, up);
  moe_gemm2<<<dim3((HD / BN2) * MAXMT), dim3(256), 0, stream>>>(up, w2, bs, out);
}

// Round 7
// 219.021 us; speedup vs baseline: 2.1454x; 2.1454x over previous
//
#include <hip/hip_runtime.h>
#include <hip/hip_bf16.h>

#define NE 8
#define HD 1024
#define ID 2816
#define TT 4096
#define BM 128
#define BK 32
#define BN1 128
#define BN2 64
#define MAXMT (TT / BM + NE) /* 40 worst-case M-tiles */

typedef __attribute__((ext_vector_type(4))) float f32x4;
typedef __attribute__((ext_vector_type(8))) short s16x8;

// fp32x2 -> packed bf16x2 (RNE, v_cvt_pk_bf16_f32)
__device__ __forceinline__ unsigned int f2bfpk(float lo, float hi) {
  float2 t; t.x = lo; t.y = hi;
  union { __hip_bfloat162 h2; unsigned int u; } cv;
  cv.h2 = __float22bfloat162_rn(t);
  return cv.u;
}

// barrier that does NOT drain vmcnt: prefetch loads stay in flight
__device__ __forceinline__ void lds_barrier() {
  asm volatile("s_waitcnt lgkmcnt(0)" ::: "memory");
  __builtin_amdgcn_s_barrier();
}

__device__ __forceinline__ bool map_tile(const void* bsp, int mt, int& e,
                                         int& mstart, int& rowend) {
  const int* w = (const int*)bsp;
  bool is64 = (w[1] == 0) && (w[3] == 0) && (w[5] == 0) && (w[7] == 0) &&
              ((w[0] | w[2] | w[4] | w[6]) != 0);
  long long start = 0;
  int rem = mt;
  for (int i = 0; i < NE; ++i) {
    long long b = is64 ? ((const long long*)bsp)[i] : (long long)w[i];
    if (b < 0) b = 0;
    int tiles = (int)((b + BM - 1) / BM);
    if (rem < tiles) {
      long long m0 = start + (long long)rem * BM;
      long long me = start + b;
      if (m0 >= TT) return false;
      if (me > TT) me = TT;
      e = i; mstart = (int)m0; rowend = (int)me;
      return true;
    }
    rem -= tiles;
    start += b;
  }
  return false;
}

// ---------------- Kernel 0: x (fp32) -> xbf (bf16) ----------------
__global__ __launch_bounds__(256) void cvt_x(const float* __restrict__ x,
                                             __hip_bfloat16* __restrict__ xb) {
  size_t i = ((size_t)blockIdx.x * 256 + threadIdx.x) * 8;
  f32x4 v0 = *(const f32x4*)(x + i);
  f32x4 v1 = *(const f32x4*)(x + i + 4);
  s16x8 o;
  unsigned int p0 = f2bfpk(v0[0], v0[1]), p1 = f2bfpk(v0[2], v0[3]);
  unsigned int p2 = f2bfpk(v1[0], v1[1]), p3 = f2bfpk(v1[2], v1[3]);
  o[0] = (short)(p0 & 0xffff); o[1] = (short)(p0 >> 16);
  o[2] = (short)(p1 & 0xffff); o[3] = (short)(p1 >> 16);
  o[4] = (short)(p2 & 0xffff); o[5] = (short)(p2 >> 16);
  o[6] = (short)(p3 & 0xffff); o[7] = (short)(p3 >> 16);
  *(s16x8*)((unsigned short*)xb + i) = o;
}

// ---------------- Kernel 1: up = silu(x@w1[e]) * (x@w3[e]) ----------------
// 512 threads, 128x128 tile, 8 waves (2m x 4n), BK=32, dual accumulators.
// B LDS: [n][80B], k 16B-contiguous -> b128 frag reads, b64 writes.
// 2-deep prefetch, vmcnt-preserving lds_barrier, 1 barrier per k-step.
// launch_bounds (512,2): 128-VGPR cap -- (512,4) forced 64 VGPR and spilled
// 300 MB to scratch (round-6 regression).
__global__ __launch_bounds__(512, 2) void moe_gemm1(
    const __hip_bfloat16* __restrict__ xbf, const float* __restrict__ w1,
    const float* __restrict__ w3, const void* __restrict__ bsp,
    __hip_bfloat16* __restrict__ up) {
  __shared__ __align__(16) char As[2][BM * 80];    // 20480
  __shared__ __align__(16) char B1s[2][BN1 * 80];  // 20480
  __shared__ __align__(16) char B3s[2][BN1 * 80];  // 20480

  const int NWG = (ID / BN1) * MAXMT;  // 22*40 = 880, %8==0
  int bid = blockIdx.x;
  int logical = (bid & 7) * (NWG >> 3) + (bid >> 3);
  int mt = logical % MAXMT;
  int nt = logical / MAXMT;
  int e, mstart, rowend;
  if (!map_tile(bsp, mt, e, mstart, rowend)) return;
  const int n0 = nt * BN1;
  const int tid = threadIdx.x;

  const int lane = tid & 63;
  const int wv = tid >> 6;          // 0..7
  const int wr = wv >> 2, wc = wv & 3;  // 2m x 4n, per-wave 64m x 32n
  const int q = lane >> 4, r16 = lane & 15;

  // staging geometry (512 threads)
  const int a_k8 = (tid & 3) * 8;   // bf16 k-offset (16B)
  const int a_r0 = tid >> 2;        // 0..127
  const int b_n = tid & 127;        // B column
  const int b_kq = tid >> 7;        // 0..3 (k-quad)

  const bool ok0 = (mstart + a_r0) < rowend;

  const __hip_bfloat16* xc = xbf + (size_t)(mstart + a_r0) * HD + a_k8;
  const float* w1c = w1 + (size_t)e * HD * ID + (size_t)(4 * b_kq) * ID + n0 + b_n;
  const float* w3c = w3 + (size_t)e * HD * ID + (size_t)(4 * b_kq) * ID + n0 + b_n;

  f32x4 acc1[4][2], acc3[4][2];
#pragma unroll
  for (int i = 0; i < 4; ++i)
#pragma unroll
    for (int j = 0; j < 2; ++j) { acc1[i][j] = (f32x4)0.f; acc3[i][j] = (f32x4)0.f; }

  // two register prefetch buffers (statically indexed)
  s16x8 A0, A1;
  float W1a[2][4], W3a[2][4], W1b[2][4], W3b[2][4];

  auto load_t = [&](s16x8& A, float (*W1_)[4], float (*W3_)[4]) {
    A = ok0 ? *(const s16x8*)xc : (s16x8)0;
    xc += BK;
#pragma unroll
    for (int g = 0; g < 2; ++g)
#pragma unroll
      for (int kk = 0; kk < 4; ++kk) {
        W1_[g][kk] = w1c[(size_t)(g * 16 + kk) * ID];
        W3_[g][kk] = w3c[(size_t)(g * 16 + kk) * ID];
      }
    w1c += (size_t)BK * ID; w3c += (size_t)BK * ID;
  };
  auto store_t = [&](char* As_, char* B1_, char* B3_, const s16x8& A,
                     const float (*W1_)[4], const float (*W3_)[4]) {
    *(s16x8*)(As_ + a_r0 * 80 + a_k8 * 2) = A;
#pragma unroll
    for (int g = 0; g < 2; ++g) {
      unsigned long long p1 =
          (unsigned long long)f2bfpk(W1_[g][0], W1_[g][1]) |
          ((unsigned long long)f2bfpk(W1_[g][2], W1_[g][3]) << 32);
      *(unsigned long long*)(B1_ + b_n * 80 + b_kq * 8 + g * 32) = p1;
      unsigned long long p3 =
          (unsigned long long)f2bfpk(W3_[g][0], W3_[g][1]) |
          ((unsigned long long)f2bfpk(W3_[g][2], W3_[g][3]) << 32);
      *(unsigned long long*)(B3_ + b_n * 80 + b_kq * 8 + g * 32) = p3;
    }
  };
  auto compute_t = [&](const char* As_, const char* B1_, const char* B3_) {
    s16x8 a[4], b1[2], b3[2];
#pragma unroll
    for (int i = 0; i < 4; ++i)
      a[i] = *(const s16x8*)(As_ + (wr * 64 + i * 16 + r16) * 80 + q * 16);
#pragma unroll
    for (int j = 0; j < 2; ++j) {
      b1[j] = *(const s16x8*)(B1_ + (wc * 32 + j * 16 + r16) * 80 + q * 16);
      b3[j] = *(const s16x8*)(B3_ + (wc * 32 + j * 16 + r16) * 80 + q * 16);
    }
#pragma unroll
    for (int i = 0; i < 4; ++i)
#pragma unroll
      for (int j = 0; j < 2; ++j) {
        acc1[i][j] = __builtin_amdgcn_mfma_f32_16x16x32_bf16(a[i], b1[j], acc1[i][j], 0, 0, 0);
        acc3[i][j] = __builtin_amdgcn_mfma_f32_16x16x32_bf16(a[i], b3[j], acc3[i][j], 0, 0, 0);
      }
  };

  const int NK = HD / BK;  // 32 (even)
  load_t(A0, W1a, W3a);
  load_t(A1, W1b, W3b);
  store_t(As[0], B1s[0], B3s[0], A0, W1a, W3a);
  lds_barrier();
  for (int kt = 0; kt < NK; kt += 2) {
    if (kt + 2 < NK) load_t(A0, W1a, W3a);
    compute_t(As[0], B1s[0], B3s[0]);
    store_t(As[1], B1s[1], B3s[1], A1, W1b, W3b);
    lds_barrier();
    if (kt + 3 < NK) load_t(A1, W1b, W3b);
    compute_t(As[1], B1s[1], B3s[1]);
    if (kt + 2 < NK) {
      store_t(As[0], B1s[0], B3s[0], A0, W1a, W3a);
      lds_barrier();
    }
  }

  // epilogue: silu(acc1)*acc3 -> bf16
#pragma unroll
  for (int i = 0; i < 4; ++i)
#pragma unroll
    for (int r = 0; r < 4; ++r) {
      int gm = mstart + wr * 64 + i * 16 + q * 4 + r;
      if (gm < rowend) {
#pragma unroll
        for (int j = 0; j < 2; ++j) {
          float v1 = acc1[i][j][r], v3 = acc3[i][j][r];
          float s = v1 / (1.f + __expf(-v1));
          up[(size_t)gm * ID + n0 + wc * 32 + j * 16 + r16] = __float2bfloat16(s * v3);
        }
      }
    }
}

// ---------------- Kernel 2: out = up @ w2[e] ----------------
// 256 threads, 128x64 tile, 4 waves (2m x 2n). Same B layout.
__global__ __launch_bounds__(256, 4) void moe_gemm2(
    const __hip_bfloat16* __restrict__ up, const float* __restrict__ w2,
    const void* __restrict__ bsp, float* __restrict__ out) {
  __shared__ __align__(16) char As[2][BM * 80];   // 20480
  __shared__ __align__(16) char Bs[2][BN2 * 80];  // 10240

  const int NWG = (HD / BN2) * MAXMT;  // 640, %8==0
  int bid = blockIdx.x;
  int logical = (bid & 7) * (NWG >> 3) + (bid >> 3);
  int mt = logical % MAXMT;
  int nt = logical / MAXMT;
  int e, mstart, rowend;
  if (!map_tile(bsp, mt, e, mstart, rowend)) return;
  const int n0 = nt * BN2;
  const int tid = threadIdx.x;

  const int lane = tid & 63;
  const int wv = tid >> 6;
  const int wr = wv >> 1, wc = wv & 1;
  const int q = lane >> 4, r16 = lane & 15;

  const int a_k8 = (tid & 3) * 8;
  const int a_r0 = tid >> 2;   // 0..63, rows {a_r0, a_r0+64}
  const int b_n = tid & 63;
  const int b_kq = tid >> 6;   // 0..3

  const bool ok0 = (mstart + a_r0) < rowend;
  const bool ok1 = (mstart + a_r0 + 64) < rowend;

  const __hip_bfloat16* uc = up + (size_t)(mstart + a_r0) * ID + a_k8;
  const float* w2c = w2 + (size_t)e * ID * HD + (size_t)(4 * b_kq) * HD + n0 + b_n;

  f32x4 acc[4][2];
#pragma unroll
  for (int i = 0; i < 4; ++i)
#pragma unroll
    for (int j = 0; j < 2; ++j) acc[i][j] = (f32x4)0.f;

  s16x8 A0[2], A1[2];
  float Wa[2][4], Wb[2][4];

  auto load_t = [&](s16x8* A, float (*W_)[4]) {
    A[0] = ok0 ? *(const s16x8*)uc : (s16x8)0;
    A[1] = ok1 ? *(const s16x8*)(uc + (size_t)64 * ID) : (s16x8)0;
    uc += BK;
#pragma unroll
    for (int g = 0; g < 2; ++g)
#pragma unroll
      for (int kk = 0; kk < 4; ++kk)
        W_[g][kk] = w2c[(size_t)(g * 16 + kk) * HD];
    w2c += (size_t)BK * HD;
  };
  auto store_t = [&](char* As_, char* B_, const s16x8* A, const float (*W_)[4]) {
    *(s16x8*)(As_ + a_r0 * 80 + a_k8 * 2) = A[0];
    *(s16x8*)(As_ + (a_r0 + 64) * 80 + a_k8 * 2) = A[1];
#pragma unroll
    for (int g = 0; g < 2; ++g) {
      unsigned long long p =
          (unsigned long long)f2bfpk(W_[g][0], W_[g][1]) |
          ((unsigned long long)f2bfpk(W_[g][2], W_[g][3]) << 32);
      *(unsigned long long*)(B_ + b_n * 80 + b_kq * 8 + g * 32) = p;
    }
  };
  auto compute_t = [&](const char* As_, const char* B_) {
    s16x8 a[4], b[2];
#pragma unroll
    for (int i = 0; i < 4; ++i)
      a[i] = *(const s16x8*)(As_ + (wr * 64 + i * 16 + r16) * 80 + q * 16);
#pragma unroll
    for (int j = 0; j < 2; ++j)
      b[j] = *(const s16x8*)(B_ + (wc * 32 + j * 16 + r16) * 80 + q * 16);
#pragma unroll
    for (int i = 0; i < 4; ++i)
#pragma unroll
      for (int j = 0; j < 2; ++j)
        acc[i][j] = __builtin_amdgcn_mfma_f32_16x16x32_bf16(a[i], b[j], acc[i][j], 0, 0, 0);
  };

  const int NK = ID / BK;  // 88 (even)
  load_t(A0, Wa);
  load_t(A1, Wb);
  store_t(As[0], Bs[0], A0, Wa);
  lds_barrier();
  for (int kt = 0; kt < NK; kt += 2) {
    if (kt + 2 < NK) load_t(A0, Wa);
    compute_t(As[0], Bs[0]);
    store_t(As[1], Bs[1], A1, Wb);
    lds_barrier();
    if (kt + 3 < NK) load_t(A1, Wb);
    compute_t(As[1], Bs[1]);
    if (kt + 2 < NK) {
      store_t(As[0], Bs[0], A0, Wa);
      lds_barrier();
    }
  }

#pragma unroll
  for (int i = 0; i < 4; ++i)
#pragma unroll
    for (int r = 0; r < 4; ++r) {
      int gm = mstart + wr * 64 + i * 16 + q * 4 + r;
      if (gm < rowend) {
#pragma unroll
        for (int j = 0; j < 2; ++j)
          out[(size_t)gm * HD + n0 + wc * 32 + j * 16 + r16] = acc[i][j][r];
      }
    }
}

extern "C" void kernel_launch(void* const* d_in, const int* in_sizes, int n_in,
                              void* d_out, int out_size, void* d_ws, size_t ws_size,
                              hipStream_t stream) {
  const float* x = (const float*)d_in[0];
  const float* w1 = (const float*)d_in[1];
  const float* w2 = (const float*)d_in[2];
  const float* w3 = (const float*)d_in[3];
  const void* bs = d_in[4];
  float* out = (float*)d_out;
  // ws layout: xbf [TT*HD bf16 = 8.39 MB] | up [TT*ID bf16 = 23.1 MB]
  __hip_bfloat16* xbf = (__hip_bfloat16*)d_ws;
  __hip_bfloat16* up = (__hip_bfloat16*)((char*)d_ws + (size_t)TT * HD * 2);

  hipMemsetAsync(d_out, 0, (size_t)out_size * sizeof(float), stream);

  cvt_x<<<dim3(TT * HD / (8 * 256)), dim3(256), 0, stream>>>(x, xbf);
  moe_gemm1<<<dim3((ID / BN1) * MAXMT), dim3(512), 0, stream>>>(xbf, w1, w3, bs, up);
  moe_gemm2<<<dim3((HD / BN2) * MAXMT), dim3(256), 0, stream>>>(up, w2, bs, out);
}

// Round 8
// 184.897 us; speedup vs baseline: 2.5414x; 1.1846x over previous
//
#include <hip/hip_runtime.h>
#include <hip/hip_bf16.h>

#define NE 8
#define HD 1024
#define ID 2816
#define TT 4096
#define BM 128
#define BK 32
#define BN1 64
#define BN2 64
#define MAXMT (TT / BM + NE) /* 40 worst-case M-tiles */
#define NKS1 (HD / BK)  /* 32 */
#define NKS2 (ID / BK)  /* 88 */
#define ATILE 8192      /* BM*BK*2B, fragment-order A tile */

typedef __attribute__((ext_vector_type(4))) float f32x4;
typedef __attribute__((ext_vector_type(8))) short s16x8;
typedef __attribute__((ext_vector_type(4))) int i32x4;

// fp32x2 -> packed bf16x2 (RNE, v_cvt_pk_bf16_f32)
__device__ __forceinline__ unsigned int f2bfpk(float lo, float hi) {
  float2 t; t.x = lo; t.y = hi;
  union { __hip_bfloat162 h2; unsigned int u; } cv;
  cv.h2 = __float22bfloat162_rn(t);
  return cv.u;
}

// barrier that does NOT drain vmcnt: prefetch loads stay in flight
__device__ __forceinline__ void lds_barrier() {
  asm volatile("s_waitcnt lgkmcnt(0)" ::: "memory");
  __builtin_amdgcn_s_barrier();
}

// async global->LDS, 16B per lane
__device__ __forceinline__ void glds16(const void* g, void* l) {
  __builtin_amdgcn_global_load_lds(
      (const __attribute__((address_space(1))) void*)g,
      (__attribute__((address_space(3))) void*)l, 16, 0, 0);
}

__device__ __forceinline__ bool map_tile(const void* bsp, int mt, int& e,
                                         int& mstart, int& rowend) {
  const int* w = (const int*)bsp;
  bool is64 = (w[1] == 0) && (w[3] == 0) && (w[5] == 0) && (w[7] == 0) &&
              ((w[0] | w[2] | w[4] | w[6]) != 0);
  long long start = 0;
  int rem = mt;
  for (int i = 0; i < NE; ++i) {
    long long b = is64 ? ((const long long*)bsp)[i] : (long long)w[i];
    if (b < 0) b = 0;
    int tiles = (int)((b + BM - 1) / BM);
    if (rem < tiles) {
      long long m0 = start + (long long)rem * BM;
      long long me = start + b;
      if (m0 >= TT) return false;
      if (me > TT) me = TT;
      e = i; mstart = (int)m0; rowend = (int)me;
      return true;
    }
    rem -= tiles;
    start += b;
  }
  return false;
}

// ---- Kernel 0: x fp32 -> bf16, PRE-TILED in MFMA fragment order ----
// Layout: [mt][ks][frag-group f=0..7][lane=0..63][8 bf16], 8192B per (mt,ks).
// Group f holds rows mstart+f*16+(lane&15), cols ks*32+(lane>>4)*8..+7.
// Rows >= rowend are zeroed (gemm1 then needs no A guards).
__global__ __launch_bounds__(256) void cvt_xt(const float* __restrict__ x,
                                              const void* __restrict__ bsp,
                                              unsigned short* __restrict__ xt) {
  int mt = blockIdx.x >> 5;
  int ks = blockIdx.x & 31;
  int e, mstart, rowend;
  if (!map_tile(bsp, mt, e, mstart, rowend)) return;
  int t = threadIdx.x;
  int lane = t & 63;
  int r = lane & 15, q = lane >> 4;
  unsigned short* ob = xt + ((size_t)mt * NKS1 + ks) * (ATILE / 2);
#pragma unroll
  for (int h = 0; h < 2; ++h) {
    int f = h * 4 + (t >> 6);
    int row = mstart + f * 16 + r;
    s16x8 o = (s16x8)0;
    if (row < rowend) {
      const float* src = x + (size_t)row * HD + ks * 32 + q * 8;
      f32x4 v0 = *(const f32x4*)src;
      f32x4 v1 = *(const f32x4*)(src + 4);
      unsigned int d0 = f2bfpk(v0[0], v0[1]), d1 = f2bfpk(v0[2], v0[3]);
      unsigned int d2 = f2bfpk(v1[0], v1[1]), d3 = f2bfpk(v1[2], v1[3]);
      o[0] = (short)d0; o[1] = (short)(d0 >> 16);
      o[2] = (short)d1; o[3] = (short)(d1 >> 16);
      o[4] = (short)d2; o[5] = (short)(d2 >> 16);
      o[6] = (short)d3; o[7] = (short)(d3 >> 16);
    }
    *(s16x8*)(ob + h * 2048 + t * 8) = o;  // coalesced 16B/thread
  }
}

// ---------------- Kernel 1: up = silu(x@w1[e]) * (x@w3[e]) ----------------
// 256 thr, 4 waves (2m x 2n, 64x32/wave), BM=128 BN=64 BK=32, dual acc.
// A: global_load_lds from pre-tiled xt into As[4] rotation, issued 2 phases
//    ahead; drained by the compiler's vmcnt wait for B-reg stores (FIFO,
//    glds issued first + sched_barrier).
// B: frag-order LDS (group*1024+lane*16): 1 b128 write/thread, 1 b128
//    read/fragment, conflict-free linear patterns.
__global__ __launch_bounds__(256, 3) void moe_gemm1(
    const unsigned short* __restrict__ xt, const float* __restrict__ w1,
    const float* __restrict__ w3, const void* __restrict__ bsp,
    __hip_bfloat16* __restrict__ up) {
  __shared__ __align__(16) char As[4][ATILE];   // 32768
  __shared__ __align__(16) char B1s[2][4096];   // 8192
  __shared__ __align__(16) char B3s[2][4096];   // 8192  -> 48KB, 3 blk/CU

  const int NWG = (ID / BN1) * MAXMT;  // 1760, %8==0
  int bid = blockIdx.x;
  int logical = (bid & 7) * (NWG >> 3) + (bid >> 3);
  int mt = logical % MAXMT;
  int nt = logical / MAXMT;
  int e, mstart, rowend;
  if (!map_tile(bsp, mt, e, mstart, rowend)) return;
  const int n0 = nt * BN1;
  const int tid = threadIdx.x;
  const int lane = tid & 63;
  const int wv = tid >> 6;
  const int wr = wv >> 1, wc = wv & 1;
  const int q = lane >> 4, r16 = lane & 15;

  // B staging: thread (b_n, b_kq) owns col n0+b_n, k = 8*b_kq .. +7
  const int b_n = tid & 63, b_kq = tid >> 6;
  const int boff = (b_n >> 4) * 1024 + b_kq * 256 + (b_n & 15) * 16;
  const char* agp = (const char*)xt + (size_t)mt * NKS1 * ATILE + tid * 16;
  const float* w1c = w1 + (size_t)e * HD * ID + (size_t)(8 * b_kq) * ID + n0 + b_n;
  const float* w3c = w3 + (size_t)e * HD * ID + (size_t)(8 * b_kq) * ID + n0 + b_n;

  f32x4 acc1[4][2], acc3[4][2];
#pragma unroll
  for (int i = 0; i < 4; ++i)
#pragma unroll
    for (int j = 0; j < 2; ++j) { acc1[i][j] = (f32x4)0.f; acc3[i][j] = (f32x4)0.f; }

  float Wa1[8], Wa3[8], Wb1[8], Wb3[8];

  auto gldsA = [&](int k, int buf) {
    const char* s = agp + (size_t)k * ATILE;
    char* d = &As[buf][0] + tid * 16;
    glds16(s, d);
    glds16(s + 4096, d + 4096);
  };
  auto loadB = [&](float* W1_, float* W3_) {
#pragma unroll
    for (int i = 0; i < 8; ++i) {
      W1_[i] = w1c[(size_t)i * ID];
      W3_[i] = w3c[(size_t)i * ID];
    }
    w1c += (size_t)BK * ID; w3c += (size_t)BK * ID;
  };
  auto storeB = [&](int buf, const float* W1_, const float* W3_) {
    i32x4 p1, p3;
    p1[0] = (int)f2bfpk(W1_[0], W1_[1]); p1[1] = (int)f2bfpk(W1_[2], W1_[3]);
    p1[2] = (int)f2bfpk(W1_[4], W1_[5]); p1[3] = (int)f2bfpk(W1_[6], W1_[7]);
    *(i32x4*)(B1s[buf] + boff) = p1;
    p3[0] = (int)f2bfpk(W3_[0], W3_[1]); p3[1] = (int)f2bfpk(W3_[2], W3_[3]);
    p3[2] = (int)f2bfpk(W3_[4], W3_[5]); p3[3] = (int)f2bfpk(W3_[6], W3_[7]);
    *(i32x4*)(B3s[buf] + boff) = p3;
  };
  auto compute = [&](int ab, int bb) {
    s16x8 a[4], b1[2], b3[2];
#pragma unroll
    for (int i = 0; i < 4; ++i)
      a[i] = *(const s16x8*)(As[ab] + (wr * 4 + i) * 1024 + lane * 16);
#pragma unroll
    for (int j = 0; j < 2; ++j) {
      b1[j] = *(const s16x8*)(B1s[bb] + (wc * 2 + j) * 1024 + lane * 16);
      b3[j] = *(const s16x8*)(B3s[bb] + (wc * 2 + j) * 1024 + lane * 16);
    }
#pragma unroll
    for (int i = 0; i < 4; ++i)
#pragma unroll
      for (int j = 0; j < 2; ++j) {
        acc1[i][j] = __builtin_amdgcn_mfma_f32_16x16x32_bf16(a[i], b1[j], acc1[i][j], 0, 0, 0);
        acc3[i][j] = __builtin_amdgcn_mfma_f32_16x16x32_bf16(a[i], b3[j], acc3[i][j], 0, 0, 0);
      }
  };

// phase K: glds A(K+2) [2 ahead], load B(K+2)->regbuf[K&1], compute K,
// store B(K+1) from regbuf[(K+1)&1] (vmcnt wait drains glds(K+1)), barrier.
#define G1PHASE(AB, GD, BB, SB, LW1, LW3, SW1, SW3, KC)    \
  if (kt + (KC) + 2 < NKS1) {                              \
    gldsA(kt + (KC) + 2, (GD));                            \
    __builtin_amdgcn_sched_barrier(0);                     \
    loadB(LW1, LW3);                                       \
  }                                                        \
  compute((AB), (BB));                                     \
  if (kt + (KC) + 1 < NKS1) {                              \
    storeB((SB), SW1, SW3);                                \
    lds_barrier();                                         \
  }

  // prologue: tiles 0,1
  gldsA(0, 0); gldsA(1, 1);
  __builtin_amdgcn_sched_barrier(0);
  loadB(Wa1, Wa3);            // tile 0
  loadB(Wb1, Wb3);            // tile 1
  storeB(0, Wa1, Wa3);        // waits B(0) -> drains glds(0),glds(1)
  lds_barrier();

  for (int kt = 0; kt < NKS1; kt += 4) {
    G1PHASE(0, 2, 0, 1, Wa1, Wa3, Wb1, Wb3, 0)
    G1PHASE(1, 3, 1, 0, Wb1, Wb3, Wa1, Wa3, 1)
    G1PHASE(2, 0, 0, 1, Wa1, Wa3, Wb1, Wb3, 2)
    G1PHASE(3, 1, 1, 0, Wb1, Wb3, Wa1, Wa3, 3)
  }
#undef G1PHASE

  // epilogue: silu(acc1)*acc3 -> bf16
#pragma unroll
  for (int i = 0; i < 4; ++i)
#pragma unroll
    for (int r = 0; r < 4; ++r) {
      int gm = mstart + wr * 64 + i * 16 + q * 4 + r;
      if (gm < rowend) {
#pragma unroll
        for (int j = 0; j < 2; ++j) {
          float v1 = acc1[i][j][r], v3 = acc3[i][j][r];
          float s = v1 / (1.f + __expf(-v1));
          up[(size_t)gm * ID + n0 + wc * 32 + j * 16 + r16] = __float2bfloat16(s * v3);
        }
      }
    }
}

// ---------------- Kernel 2: out = up @ w2[e] ----------------
// 256 thr, 128x64, 4 waves. A reg-staged (bf16, [128][80B] LDS); B frag-order.
__global__ __launch_bounds__(256, 3) void moe_gemm2(
    const __hip_bfloat16* __restrict__ up, const float* __restrict__ w2,
    const void* __restrict__ bsp, float* __restrict__ out) {
  __shared__ __align__(16) char As[2][BM * 80];  // 20480
  __shared__ __align__(16) char Bs[2][4096];     // 8192  -> 28KB

  const int NWG = (HD / BN2) * MAXMT;  // 640, %8==0
  int bid = blockIdx.x;
  int logical = (bid & 7) * (NWG >> 3) + (bid >> 3);
  int mt = logical % MAXMT;
  int nt = logical / MAXMT;
  int e, mstart, rowend;
  if (!map_tile(bsp, mt, e, mstart, rowend)) return;
  const int n0 = nt * BN2;
  const int tid = threadIdx.x;
  const int lane = tid & 63;
  const int wv = tid >> 6;
  const int wr = wv >> 1, wc = wv & 1;
  const int q = lane >> 4, r16 = lane & 15;

  const int a_k8 = (tid & 3) * 8;
  const int a_r0 = tid >> 2;  // rows {a_r0, a_r0+64}
  const int b_n = tid & 63, b_kq = tid >> 6;
  const int boff = (b_n >> 4) * 1024 + b_kq * 256 + (b_n & 15) * 16;

  const bool ok0 = (mstart + a_r0) < rowend;
  const bool ok1 = (mstart + a_r0 + 64) < rowend;

  const __hip_bfloat16* uc = up + (size_t)(mstart + a_r0) * ID + a_k8;
  const float* w2c = w2 + (size_t)e * ID * HD + (size_t)(8 * b_kq) * HD + n0 + b_n;

  f32x4 acc[4][2];
#pragma unroll
  for (int i = 0; i < 4; ++i)
#pragma unroll
    for (int j = 0; j < 2; ++j) acc[i][j] = (f32x4)0.f;

  s16x8 Aa[2], Ab[2];
  float Wa[8], Wb[8];

  auto loadT = [&](s16x8* A, float* W_) {
    A[0] = ok0 ? *(const s16x8*)uc : (s16x8)0;
    A[1] = ok1 ? *(const s16x8*)(uc + (size_t)64 * ID) : (s16x8)0;
    uc += BK;
#pragma unroll
    for (int i = 0; i < 8; ++i) W_[i] = w2c[(size_t)i * HD];
    w2c += (size_t)BK * HD;
  };
  auto storeT = [&](int buf, const s16x8* A, const float* W_) {
    *(s16x8*)(As[buf] + a_r0 * 80 + a_k8 * 2) = A[0];
    *(s16x8*)(As[buf] + (a_r0 + 64) * 80 + a_k8 * 2) = A[1];
    i32x4 p;
    p[0] = (int)f2bfpk(W_[0], W_[1]); p[1] = (int)f2bfpk(W_[2], W_[3]);
    p[2] = (int)f2bfpk(W_[4], W_[5]); p[3] = (int)f2bfpk(W_[6], W_[7]);
    *(i32x4*)(Bs[buf] + boff) = p;
  };
  auto compute = [&](int buf) {
    s16x8 a[4], b[2];
#pragma unroll
    for (int i = 0; i < 4; ++i)
      a[i] = *(const s16x8*)(As[buf] + (wr * 64 + i * 16 + r16) * 80 + q * 16);
#pragma unroll
    for (int j = 0; j < 2; ++j)
      b[j] = *(const s16x8*)(Bs[buf] + (wc * 2 + j) * 1024 + lane * 16);
#pragma unroll
    for (int i = 0; i < 4; ++i)
#pragma unroll
      for (int j = 0; j < 2; ++j)
        acc[i][j] = __builtin_amdgcn_mfma_f32_16x16x32_bf16(a[i], b[j], acc[i][j], 0, 0, 0);
  };

#define G2PHASE(AB, SB, LA, LW, SA, SW, KC)                 \
  if (kt + (KC) + 2 < NKS2) { loadT(LA, LW); }              \
  compute(AB);                                              \
  if (kt + (KC) + 1 < NKS2) { storeT((SB), SA, SW); lds_barrier(); }

  loadT(Aa, Wa);        // tile 0
  loadT(Ab, Wb);        // tile 1
  storeT(0, Aa, Wa);
  lds_barrier();
  for (int kt = 0; kt < NKS2; kt += 2) {
    G2PHASE(0, 1, Aa, Wa, Ab, Wb, 0)
    G2PHASE(1, 0, Ab, Wb, Aa, Wa, 1)
  }
#undef G2PHASE

#pragma unroll
  for (int i = 0; i < 4; ++i)
#pragma unroll
    for (int r = 0; r < 4; ++r) {
      int gm = mstart + wr * 64 + i * 16 + q * 4 + r;
      if (gm < rowend) {
#pragma unroll
        for (int j = 0; j < 2; ++j)
          out[(size_t)gm * HD + n0 + wc * 32 + j * 16 + r16] = acc[i][j][r];
      }
    }
}

extern "C" void kernel_launch(void* const* d_in, const int* in_sizes, int n_in,
                              void* d_out, int out_size, void* d_ws, size_t ws_size,
                              hipStream_t stream) {
  const float* x = (const float*)d_in[0];
  const float* w1 = (const float*)d_in[1];
  const float* w2 = (const float*)d_in[2];
  const float* w3 = (const float*)d_in[3];
  const void* bs = d_in[4];
  float* out = (float*)d_out;
  // ws: xt tiled [MAXMT*32*8192B = 10.49 MB] | up [TT*ID*2B = 23.07 MB]
  unsigned short* xt = (unsigned short*)d_ws;
  __hip_bfloat16* up =
      (__hip_bfloat16*)((char*)d_ws + (size_t)MAXMT * NKS1 * ATILE);

  hipMemsetAsync(d_out, 0, (size_t)out_size * sizeof(float), stream);

  cvt_xt<<<dim3(MAXMT * NKS1), dim3(256), 0, stream>>>(x, bs, xt);
  moe_gemm1<<<dim3((ID / BN1) * MAXMT), dim3(256), 0, stream>>>(xt, w1, w3, bs, up);
  moe_gemm2<<<dim3((HD / BN2) * MAXMT), dim3(256), 0, stream>>>(up, w2, bs, out);
}